// Round 1
// baseline (274.296 us; speedup 1.0000x reference)
//
#include <hip/hip_runtime.h>
#include <hip/hip_bf16.h>
#include <cstdint>
#include <cstddef>

// Problem constants (shapes fixed by the reference)
#define NN      10000      // nodes (M == N == 10000)
#define DD      256        // feature dim
#define KSTEPS  313        // ceil(10016/32) K-steps of 32 over padded K
#define BM      80         // rows per block in big GEMM (125 * 80 == 10000 exactly)
#define MBLKS   125
#define KSPLIT  4
#define NB      272        // 256 value cols + 16-col tile holding the denominator (col 256)

typedef __bf16 bf16x8 __attribute__((ext_vector_type(8)));
typedef float  f32x4  __attribute__((ext_vector_type(4)));

// ---- workspace layout (bytes) ----
#define XG_OFF   0ull
#define XG_SIZE  (32ull * 10000 * 16)        // [q=kb*4+g][row] 16B chunks (bf16 X, MFMA-A layout)
#define WG_OFF   (XG_OFF + XG_SIZE)
#define WG_SIZE  (32ull * 256 * 16)          // [q][n] chunks (bf16 W, MFMA-B layout)
#define INP_OFF  (WG_OFF + WG_SIZE)
#define INP_SIZE (10000ull * 256 * 4)        // inp = X@W, f32
#define E_OFF    (INP_OFF + INP_SIZE)
#define E_SIZE   (10016ull * 4)
#define HS_OFF   (E_OFF + E_SIZE)
#define HS_SIZE  (10016ull * 4)
#define G_OFF    (HS_OFF + HS_SIZE)
#define G_SIZE   (10016ull * 4)
#define YG_OFF   (G_OFF + G_SIZE + 256ull)   // keep 256B alignment
#define YG_SIZE  (313ull * 1088 * 16)        // [kb][chunk] pre-chunked B tiles (bf16 Y)
#define NUM_OFF  (YG_OFF + YG_SIZE)
#define NUM_SIZE (10000ull * 272 * 4)        // f32 accumulator: 256 numer cols + den at col 256

// async global(16B) -> LDS copy; dest = wave-uniform base + lane*16
__device__ __forceinline__ void gl_lds16(const void* g, void* lds) {
    __builtin_amdgcn_global_load_lds(
        (const __attribute__((address_space(1))) unsigned int*)g,
        (__attribute__((address_space(3))) unsigned int*)lds,
        16, 0, 0);
}

// ---------------- K0a: build XG (bf16 X in MFMA-A chunk layout) ----------------
// chunk q = kb*4+g (0..31) holds X[row][q*8 .. q*8+7] as bf16x8 at XG[q*10000 + row]
__global__ __launch_bounds__(256) void k_build_xg(const float* __restrict__ X,
                                                  bf16x8* __restrict__ XG) {
    int idx = blockIdx.x * 256 + threadIdx.x;   // 0..319999
    int row = idx >> 5;
    int q   = idx & 31;
    const float* src = X + row * 256 + q * 8;
    bf16x8 v;
#pragma unroll
    for (int j = 0; j < 8; ++j) v[j] = (__bf16)src[j];
    XG[q * 10000 + row] = v;
}

// ---------------- K0b: build WG (bf16 W in MFMA-B chunk layout) ----------------
// entry e = q*256 + n holds W[q*8+j][n], j=0..7
__global__ __launch_bounds__(256) void k_build_wg(const float* __restrict__ W,
                                                  bf16x8* __restrict__ WG) {
    int e = blockIdx.x * 256 + threadIdx.x;     // 0..8191
    int q = e >> 8;
    int n = e & 255;
    bf16x8 v;
#pragma unroll
    for (int j = 0; j < 8; ++j) v[j] = (__bf16)W[(q * 8 + j) * 256 + n];
    WG[e] = v;
}

// ---------------- K1: inp = X@W (MFMA), fused tanh/e/hsum ----------------
// 125 blocks x 256 thr; 4 waves col-split (each wave: 4 col-tiles x 5 row-tiles)
__global__ __launch_bounds__(256) void k_gemm1(const bf16x8* __restrict__ XG,
                                               const bf16x8* __restrict__ WG,
                                               const float* __restrict__ bvec,
                                               const float* __restrict__ avec,
                                               float* __restrict__ inp,
                                               float* __restrict__ evec,
                                               float* __restrict__ hsumv) {
    __shared__ bf16x8 Ash[320];    // (g*80 + r)
    __shared__ bf16x8 Bsh[1024];   // (g*256 + n)
    int tid = threadIdx.x, wid = tid >> 6, lane = tid & 63;
    int l15 = lane & 15, l4 = lane >> 4;
    int mb = blockIdx.x;

    f32x4 acc[4][5];
#pragma unroll
    for (int c = 0; c < 4; ++c)
#pragma unroll
        for (int rt = 0; rt < 5; ++rt) acc[c][rt] = f32x4{0.f, 0.f, 0.f, 0.f};

    for (int kb = 0; kb < 8; ++kb) {
        // stage A: 320 chunks = 5 wave-rounds
        for (int rr = wid; rr < 5; rr += 4) {
            int c = rr * 64 + lane;
            int g = c / 80, r = c - g * 80;
            gl_lds16(XG + ((kb * 4 + g) * 10000 + mb * 80 + r), (char*)Ash + rr * 1024);
        }
        // stage B: 1024 chunks = 16 wave-rounds
        for (int rr = wid; rr < 16; rr += 4)
            gl_lds16(WG + kb * 1024 + rr * 64 + lane, (char*)Bsh + rr * 1024);
        __syncthreads();

        bf16x8 af[5];
#pragma unroll
        for (int rt = 0; rt < 5; ++rt) af[rt] = Ash[l4 * 80 + rt * 16 + l15];
#pragma unroll
        for (int c = 0; c < 4; ++c) {
            bf16x8 bf = Bsh[l4 * 256 + (wid * 4 + c) * 16 + l15];
#pragma unroll
            for (int rt = 0; rt < 5; ++rt)
                acc[c][rt] = __builtin_amdgcn_mfma_f32_16x16x32_bf16(af[rt], bf, acc[c][rt], 0, 0, 0);
        }
        __syncthreads();
    }

    // epilogue: store inp, accumulate e (h@a) and hsum per row
    float pe[5][4], ph[5][4];
#pragma unroll
    for (int rt = 0; rt < 5; ++rt)
#pragma unroll
        for (int rg = 0; rg < 4; ++rg) { pe[rt][rg] = 0.f; ph[rt][rg] = 0.f; }

#pragma unroll
    for (int c = 0; c < 4; ++c) {
        int col = (wid * 4 + c) * 16 + l15;
        float av = avec[col];
        float bv = bvec[col];
#pragma unroll
        for (int rt = 0; rt < 5; ++rt) {
#pragma unroll
            for (int rg = 0; rg < 4; ++rg) {
                int row = mb * 80 + rt * 16 + l4 * 4 + rg;
                float v = acc[c][rt][rg];            // inp excludes bias (per reference)
                inp[row * 256 + col] = v;
                float h = tanhf(v + bv);
                pe[rt][rg] += h * av;
                ph[rt][rg] += h;
            }
        }
    }
#pragma unroll
    for (int rt = 0; rt < 5; ++rt) {
#pragma unroll
        for (int rg = 0; rg < 4; ++rg) {
            float se = pe[rt][rg], sh = ph[rt][rg];
#pragma unroll
            for (int m = 1; m < 16; m <<= 1) {
                se += __shfl_xor(se, m);
                sh += __shfl_xor(sh, m);
            }
            if (l15 == 0) {
                int row = mb * 80 + rt * 16 + l4 * 4 + rg;
                atomicAdd(evec + row, se);
                atomicAdd(hsumv + row, sh);
            }
        }
    }
}

// ---------------- K2: global max of e over valid nodes, then g = exp(e-gmax) ----------------
__global__ __launch_bounds__(1024) void k_softmax_g(const float* __restrict__ evec,
                                                    const float* __restrict__ hsumv,
                                                    float* __restrict__ gv) {
    __shared__ float red[1024];
    int tid = threadIdx.x;
    float m = -3.0e38f;
    for (int i = tid; i < NN; i += 1024)
        if (hsumv[i] != 0.0f) m = fmaxf(m, evec[i]);
    red[tid] = m;
    __syncthreads();
    for (int s = 512; s > 0; s >>= 1) {
        if (tid < s) red[tid] = fmaxf(red[tid], red[tid + s]);
        __syncthreads();
    }
    float gmax = red[0];
    if (gmax < -1.0e37f) gmax = 0.0f;   // no valid node: all g = 0 anyway
    for (int i = tid; i < 10016; i += 1024) {
        float g = 0.0f;
        if (i < NN && hsumv[i] != 0.0f) g = expf(evec[i] - gmax);
        gv[i] = g;
    }
}

// ---------------- K3: build YG = pre-chunked bf16 B tiles for the big GEMM ----------------
// per kb (32 K-rows): chunk c = g*272+n holds Y[kb*32+g*8+j][n]; col 256 = g_k; pads 0
__global__ __launch_bounds__(256) void k_build_yg(const float* __restrict__ inp,
                                                  const float* __restrict__ gv,
                                                  bf16x8* __restrict__ YG) {
    int kb = blockIdx.x;   // 0..312
    for (int c = threadIdx.x; c < 1088; c += 256) {
        int gq = c / 272, n = c - gq * 272;
        int k0 = kb * 32 + gq * 8;
        bf16x8 v;
#pragma unroll
        for (int j = 0; j < 8; ++j) {
            int k = k0 + j;
            float val = 0.0f;
            if (k < NN) {
                float gk = gv[k];
                if (n < 256) val = gk * inp[k * 256 + n];
                else if (n == 256) val = gk;
            }
            v[j] = (__bf16)val;
        }
        YG[kb * 1088 + c] = v;
    }
}

// ---------------- K4: num = adj @ Y  (the 400MB / 5.5e13-FLOP kernel) ----------------
// 500 blocks (125 m-blocks x KSPLIT=4), 256 thr = 4 waves col-split; f32 atomic partials
__global__ __launch_bounds__(256) void k_attn_gemm(const int* __restrict__ adj,
                                                   const bf16x8* __restrict__ YG,
                                                   float* __restrict__ numv) {
    __shared__ bf16x8 Ash[320];    // (g*80 + r) : adj tile as bf16
    __shared__ bf16x8 Bsh[1088];   // (g*272 + n)
    int tid = threadIdx.x, wid = tid >> 6, lane = tid & 63;
    int l15 = lane & 15, l4 = lane >> 4;
    int bid = blockIdx.x;
    int mb = bid % MBLKS, kc = bid / MBLKS;
    int s0 = (kc * KSTEPS) / KSPLIT, s1 = ((kc + 1) * KSTEPS) / KSPLIT;

    f32x4 acc[5][5];
#pragma unroll
    for (int c = 0; c < 5; ++c)
#pragma unroll
        for (int rt = 0; rt < 5; ++rt) acc[c][rt] = f32x4{0.f, 0.f, 0.f, 0.f};

    // A-staging assignment: thread -> entry tid (all), entry 256+tid (tid<64)
    int g0 = tid / 80, r0 = tid - g0 * 80;
    int g1 = 3, r1 = tid + 16;     // entries 256..319 are g=3, r=16..79

    const __bf16 one = (__bf16)1.0f, zer = (__bf16)0.0f;

    for (int s = s0; s < s1; ++s) {
        int k0 = s * 32;
        // ---- stage A: load int32 adj, convert to bf16 {0,1}, ds_write ----
        {
            int kbase = k0 + g0 * 8;
            bf16x8 v;
            if (kbase < NN) {   // kbase multiple of 8 => kbase+8 <= 10000 when < 10000
                const int4* p = (const int4*)(adj + (mb * 80 + r0) * 10000 + kbase);
                int4 u0 = p[0], u1 = p[1];
                v[0] = u0.x > 0 ? one : zer;  v[1] = u0.y > 0 ? one : zer;
                v[2] = u0.z > 0 ? one : zer;  v[3] = u0.w > 0 ? one : zer;
                v[4] = u1.x > 0 ? one : zer;  v[5] = u1.y > 0 ? one : zer;
                v[6] = u1.z > 0 ? one : zer;  v[7] = u1.w > 0 ? one : zer;
            } else {
#pragma unroll
                for (int j = 0; j < 8; ++j) v[j] = zer;
            }
            Ash[tid] = v;
            if (tid < 64) {
                int kbase1 = k0 + g1 * 8;
                bf16x8 w;
                if (kbase1 < NN) {
                    const int4* p = (const int4*)(adj + (mb * 80 + r1) * 10000 + kbase1);
                    int4 u0 = p[0], u1 = p[1];
                    w[0] = u0.x > 0 ? one : zer;  w[1] = u0.y > 0 ? one : zer;
                    w[2] = u0.z > 0 ? one : zer;  w[3] = u0.w > 0 ? one : zer;
                    w[4] = u1.x > 0 ? one : zer;  w[5] = u1.y > 0 ? one : zer;
                    w[6] = u1.z > 0 ? one : zer;  w[7] = u1.w > 0 ? one : zer;
                } else {
#pragma unroll
                    for (int j = 0; j < 8; ++j) w[j] = zer;
                }
                Ash[256 + tid] = w;
            }
        }
        // ---- stage B: 1088 chunks = 17 wave-rounds via global_load_lds ----
        for (int rr = wid; rr < 17; rr += 4)
            gl_lds16(YG + s * 1088 + rr * 64 + lane, (char*)Bsh + rr * 1024);
        __syncthreads();

        bf16x8 af[5];
#pragma unroll
        for (int rt = 0; rt < 5; ++rt) af[rt] = Ash[l4 * 80 + rt * 16 + l15];
#pragma unroll
        for (int c = 0; c < 5; ++c) {
            if (c == 4 && wid != 0) continue;         // only wave0 owns the den tile (ct=16)
            int ct = (c == 4) ? 16 : wid * 4 + c;
            bf16x8 bf = Bsh[l4 * 272 + ct * 16 + l15];
#pragma unroll
            for (int rt = 0; rt < 5; ++rt)
                acc[c][rt] = __builtin_amdgcn_mfma_f32_16x16x32_bf16(af[rt], bf, acc[c][rt], 0, 0, 0);
        }
        __syncthreads();
    }

    // epilogue: atomic f32 partial accumulation (rows are exact: 125*80 == 10000)
#pragma unroll
    for (int c = 0; c < 5; ++c) {
        if (c == 4 && wid != 0) continue;
        int ct = (c == 4) ? 16 : wid * 4 + c;
        int col = ct * 16 + l15;
#pragma unroll
        for (int rt = 0; rt < 5; ++rt) {
#pragma unroll
            for (int rg = 0; rg < 4; ++rg) {
                int row = mb * 80 + rt * 16 + l4 * 4 + rg;
                atomicAdd(numv + row * 272 + col, acc[c][rt][rg]);
            }
        }
    }
}

// ---------------- K5: out = num / max(den, 1e-30) ----------------
__global__ __launch_bounds__(256) void k_finalize(const float* __restrict__ numv,
                                                  float* __restrict__ out) {
    int idx = blockIdx.x * 256 + threadIdx.x;   // 0..639999 (float4 units)
    int i = idx >> 6, q = idx & 63;
    const float4* nrow = (const float4*)(numv + i * 272);
    float4 v = nrow[q];
    float den = numv[i * 272 + 256];
    float r = 1.0f / fmaxf(den, 1e-30f);
    float4 o;
    o.x = v.x * r; o.y = v.y * r; o.z = v.z * r; o.w = v.w * r;
    ((float4*)(out + i * 256))[q] = o;
}

extern "C" void kernel_launch(void* const* d_in, const int* in_sizes, int n_in,
                              void* d_out, int out_size, void* d_ws, size_t ws_size,
                              hipStream_t stream) {
    const float* X    = (const float*)d_in[0];
    const int*   adj  = (const int*)d_in[1];
    // d_in[2] is M (== 10000), fixed by the problem shapes
    const float* W    = (const float*)d_in[3];
    const float* bvec = (const float*)d_in[4];
    const float* avec = (const float*)d_in[5];
    float* out = (float*)d_out;

    char* ws = (char*)d_ws;
    bf16x8* XG   = (bf16x8*)(ws + XG_OFF);
    bf16x8* WG   = (bf16x8*)(ws + WG_OFF);
    float*  inp  = (float*)(ws + INP_OFF);
    float*  evec = (float*)(ws + E_OFF);
    float*  hsv  = (float*)(ws + HS_OFF);
    float*  gv   = (float*)(ws + G_OFF);
    bf16x8* YG   = (bf16x8*)(ws + YG_OFF);
    float*  numv = (float*)(ws + NUM_OFF);

    // zero the accumulators we atomically add into (every call; harness doesn't re-poison)
    hipMemsetAsync(ws + E_OFF, 0, E_SIZE + HS_SIZE, stream);
    hipMemsetAsync(ws + NUM_OFF, 0, NUM_SIZE, stream);

    k_build_xg<<<1250, 256, 0, stream>>>(X, XG);
    k_build_wg<<<32, 256, 0, stream>>>(W, WG);
    k_gemm1<<<125, 256, 0, stream>>>(XG, WG, bvec, avec, inp, evec, hsv);
    k_softmax_g<<<1, 1024, 0, stream>>>(evec, hsv, gv);
    k_build_yg<<<313, 256, 0, stream>>>(inp, gv, YG);
    k_attn_gemm<<<MBLKS * KSPLIT, 256, 0, stream>>>(adj, YG, numv);
    k_finalize<<<2500, 256, 0, stream>>>(numv, out);
}

// Round 2
// 224.079 us; speedup vs baseline: 1.2241x; 1.2241x over previous
//
#include <hip/hip_runtime.h>
#include <hip/hip_bf16.h>
#include <cstdint>
#include <cstddef>

// Problem constants (shapes fixed by the reference)
#define NN      10000      // nodes (M == N == 10000)
#define DD      256        // feature dim
#define KSTEPS  313        // ceil(10016/32) K-steps of 32 over padded K
#define MB2     79         // ceil(10000/128) m-blocks for big GEMM (BM=128)
#define KSPLIT  6          // 79*6 = 474 blocks  (~93% CU balance at 2 blocks/CU)

typedef __bf16 bf16x8 __attribute__((ext_vector_type(8)));
typedef float  f32x4  __attribute__((ext_vector_type(4)));

// ---- workspace layout (bytes) ----
#define XG_OFF   0ull
#define XG_SIZE  (32ull * 10000 * 16)        // [q=kb*4+g][row] 16B chunks (bf16 X, MFMA-A layout)
#define WG_OFF   (XG_OFF + XG_SIZE)
#define WG_SIZE  (32ull * 256 * 16)          // [q][n] chunks (bf16 W, MFMA-B layout)
#define INP_OFF  (WG_OFF + WG_SIZE)
#define INP_SIZE (10000ull * 256 * 4)        // inp = X@W, f32
#define E_OFF    (INP_OFF + INP_SIZE)
#define E_SIZE   (10016ull * 4)
#define HS_OFF   (E_OFF + E_SIZE)
#define HS_SIZE  (10016ull * 4)
#define G_OFF    (HS_OFF + HS_SIZE)
#define G_SIZE   (10016ull * 4)
#define YG_OFF   (G_OFF + G_SIZE + 256ull)   // keep 256B alignment
#define YG_SIZE  (314ull * 1088 * 16)        // [kb][chunk]; 314 = 313 + 1 pad kb for safe prefetch
#define NUM_OFF  (YG_OFF + YG_SIZE)
#define NUM_SIZE (10000ull * 272 * 4)        // f32 accumulator: 256 numer cols + den at col 256

// async global(16B) -> LDS copy; dest = wave-uniform base + lane*16
__device__ __forceinline__ void gl_lds16(const void* g, void* lds) {
    __builtin_amdgcn_global_load_lds(
        (const __attribute__((address_space(1))) unsigned int*)g,
        (__attribute__((address_space(3))) unsigned int*)lds,
        16, 0, 0);
}

// ---------------- K0a: build XG (bf16 X in MFMA-A chunk layout) ----------------
__global__ __launch_bounds__(256) void k_build_xg(const float* __restrict__ X,
                                                  bf16x8* __restrict__ XG) {
    int idx = blockIdx.x * 256 + threadIdx.x;   // 0..319999
    int row = idx >> 5;
    int q   = idx & 31;
    const float* src = X + row * 256 + q * 8;
    bf16x8 v;
#pragma unroll
    for (int j = 0; j < 8; ++j) v[j] = (__bf16)src[j];
    XG[q * 10000 + row] = v;
}

// ---------------- K0b: build WG (bf16 W in MFMA-B chunk layout) ----------------
__global__ __launch_bounds__(256) void k_build_wg(const float* __restrict__ W,
                                                  bf16x8* __restrict__ WG) {
    int e = blockIdx.x * 256 + threadIdx.x;     // 0..8191
    int q = e >> 8;
    int n = e & 255;
    bf16x8 v;
#pragma unroll
    for (int j = 0; j < 8; ++j) v[j] = (__bf16)W[(q * 8 + j) * 256 + n];
    WG[e] = v;
}

// ---------------- K1: inp = X@W (MFMA), fused tanh/e/hsum ----------------
__global__ __launch_bounds__(256) void k_gemm1(const bf16x8* __restrict__ XG,
                                               const bf16x8* __restrict__ WG,
                                               const float* __restrict__ bvec,
                                               const float* __restrict__ avec,
                                               float* __restrict__ inp,
                                               float* __restrict__ evec,
                                               float* __restrict__ hsumv) {
    __shared__ bf16x8 Ash[320];    // (g*80 + r)
    __shared__ bf16x8 Bsh[1024];   // (g*256 + n)
    int tid = threadIdx.x, wid = tid >> 6, lane = tid & 63;
    int l15 = lane & 15, l4 = lane >> 4;
    int mb = blockIdx.x;

    f32x4 acc[4][5];
#pragma unroll
    for (int c = 0; c < 4; ++c)
#pragma unroll
        for (int rt = 0; rt < 5; ++rt) acc[c][rt] = f32x4{0.f, 0.f, 0.f, 0.f};

    for (int kb = 0; kb < 8; ++kb) {
        for (int rr = wid; rr < 5; rr += 4) {
            int c = rr * 64 + lane;
            int g = c / 80, r = c - g * 80;
            gl_lds16(XG + ((kb * 4 + g) * 10000 + mb * 80 + r), (char*)Ash + rr * 1024);
        }
        for (int rr = wid; rr < 16; rr += 4)
            gl_lds16(WG + kb * 1024 + rr * 64 + lane, (char*)Bsh + rr * 1024);
        __syncthreads();

        bf16x8 af[5];
#pragma unroll
        for (int rt = 0; rt < 5; ++rt) af[rt] = Ash[l4 * 80 + rt * 16 + l15];
#pragma unroll
        for (int c = 0; c < 4; ++c) {
            bf16x8 bf = Bsh[l4 * 256 + (wid * 4 + c) * 16 + l15];
#pragma unroll
            for (int rt = 0; rt < 5; ++rt)
                acc[c][rt] = __builtin_amdgcn_mfma_f32_16x16x32_bf16(af[rt], bf, acc[c][rt], 0, 0, 0);
        }
        __syncthreads();
    }

    float pe[5][4], ph[5][4];
#pragma unroll
    for (int rt = 0; rt < 5; ++rt)
#pragma unroll
        for (int rg = 0; rg < 4; ++rg) { pe[rt][rg] = 0.f; ph[rt][rg] = 0.f; }

#pragma unroll
    for (int c = 0; c < 4; ++c) {
        int col = (wid * 4 + c) * 16 + l15;
        float av = avec[col];
        float bv = bvec[col];
#pragma unroll
        for (int rt = 0; rt < 5; ++rt) {
#pragma unroll
            for (int rg = 0; rg < 4; ++rg) {
                int row = mb * 80 + rt * 16 + l4 * 4 + rg;
                float v = acc[c][rt][rg];            // inp excludes bias (per reference)
                inp[row * 256 + col] = v;
                float h = tanhf(v + bv);
                pe[rt][rg] += h * av;
                ph[rt][rg] += h;
            }
        }
    }
#pragma unroll
    for (int rt = 0; rt < 5; ++rt) {
#pragma unroll
        for (int rg = 0; rg < 4; ++rg) {
            float se = pe[rt][rg], sh = ph[rt][rg];
#pragma unroll
            for (int m = 1; m < 16; m <<= 1) {
                se += __shfl_xor(se, m);
                sh += __shfl_xor(sh, m);
            }
            if (l15 == 0) {
                int row = mb * 80 + rt * 16 + l4 * 4 + rg;
                atomicAdd(evec + row, se);
                atomicAdd(hsumv + row, sh);
            }
        }
    }
}

// ---------------- K2: global max of e over valid nodes, then g = exp(e-gmax) ----------------
__global__ __launch_bounds__(1024) void k_softmax_g(const float* __restrict__ evec,
                                                    const float* __restrict__ hsumv,
                                                    float* __restrict__ gv) {
    __shared__ float red[1024];
    int tid = threadIdx.x;
    float m = -3.0e38f;
    for (int i = tid; i < NN; i += 1024)
        if (hsumv[i] != 0.0f) m = fmaxf(m, evec[i]);
    red[tid] = m;
    __syncthreads();
    for (int s = 512; s > 0; s >>= 1) {
        if (tid < s) red[tid] = fmaxf(red[tid], red[tid + s]);
        __syncthreads();
    }
    float gmax = red[0];
    if (gmax < -1.0e37f) gmax = 0.0f;
    for (int i = tid; i < 10016; i += 1024) {
        float g = 0.0f;
        if (i < NN && hsumv[i] != 0.0f) g = expf(evec[i] - gmax);
        gv[i] = g;
    }
}

// ---------------- K3: build YG = pre-chunked bf16 B tiles for the big GEMM ----------------
__global__ __launch_bounds__(256) void k_build_yg(const float* __restrict__ inp,
                                                  const float* __restrict__ gv,
                                                  bf16x8* __restrict__ YG) {
    int kb = blockIdx.x;   // 0..312
    for (int c = threadIdx.x; c < 1088; c += 256) {
        int gq = c / 272, n = c - gq * 272;
        int k0 = kb * 32 + gq * 8;
        bf16x8 v;
#pragma unroll
        for (int j = 0; j < 8; ++j) {
            int k = k0 + j;
            float val = 0.0f;
            if (k < NN) {
                float gk = gv[k];
                if (n < 256) val = gk * inp[k * 256 + n];
                else if (n == 256) val = gk;
            }
            v[j] = (__bf16)val;
        }
        YG[kb * 1088 + c] = v;
    }
}

// ---- int32 {0,1} pair-of-int4 -> bf16x8 {0,1} fragment ----
__device__ __forceinline__ bf16x8 cvt_adj(int4 a, int4 b) {
    union { bf16x8 v; unsigned int u[4]; } r;
    r.u[0] = (a.x > 0 ? 0x3F80u : 0u) | (a.y > 0 ? 0x3F800000u : 0u);
    r.u[1] = (a.z > 0 ? 0x3F80u : 0u) | (a.w > 0 ? 0x3F800000u : 0u);
    r.u[2] = (b.x > 0 ? 0x3F80u : 0u) | (b.y > 0 ? 0x3F800000u : 0u);
    r.u[3] = (b.z > 0 ? 0x3F80u : 0u) | (b.w > 0 ? 0x3F800000u : 0u);
    return r.v;
}

// ---------------- K4: num = adj @ Y  (pipelined: A->reg prefetch, B dbuf LDS) ----------------
// BM=128: 4 waves x 32 rows (2 row-tiles); all 17 col-tiles per wave.
// Per K-step: stage B(s+1) via gl_lds, prefetch A(s+1) to regs (kept in flight
// across the barrier via counted vmcnt(4)), compute step s (34 MFMA/wave).
__global__ __launch_bounds__(256, 2) void k_attn_gemm(const int* __restrict__ adj,
                                                      const bf16x8* __restrict__ YG,
                                                      float* __restrict__ numv) {
    __shared__ bf16x8 Bsh[2][1088];   // double-buffered B tiles (34816 B)
    int tid = threadIdx.x, wid = tid >> 6, lane = tid & 63;
    int l15 = lane & 15, l4 = lane >> 4;
    int bid = blockIdx.x;
    int mb = bid / KSPLIT, kc = bid % KSPLIT;   // kc fast => same-kc spreads over XCDs; YG is L3-resident anyway
    int s0 = (kc * KSTEPS) / KSPLIT, s1 = ((kc + 1) * KSTEPS) / KSPLIT;

    // A addressing: row = l15 (+16 for tile1), k-group = l4*8  (verified A-frag layout)
    int mrow = mb * 128 + wid * 32 + l15;
    size_t rA = (size_t)min(mrow, NN - 1);
    size_t rB = (size_t)min(mrow + 16, NN - 1);
    const int* pA = adj + rA * 10000;
    const int* pB = adj + rB * 10000;
    int kgrp = l4 * 8;

    f32x4 acc[2][17];
#pragma unroll
    for (int t = 0; t < 2; ++t)
#pragma unroll
        for (int ct = 0; ct < 17; ++ct) acc[t][ct] = f32x4{0.f, 0.f, 0.f, 0.f};

    // ---- prologue: stage B(s0), issue A(s0) ----
    {
        const bf16x8* src = YG + (size_t)s0 * 1088;
        char* dst = (char*)&Bsh[0][0];
#pragma unroll
        for (int i = 0; i < 4; ++i) {
            int rr = wid + i * 4;
            gl_lds16(src + rr * 64 + lane, dst + rr * 1024);
        }
        if (wid == 0) gl_lds16(src + 1024 + lane, dst + 16384);
    }
    __builtin_amdgcn_sched_barrier(0);
    int4 areg[4];
    {
        int kk = s0 * 32 + kgrp; kk = min(kk, 9992);
        const int4* qa = (const int4*)(pA + kk);
        const int4* qb = (const int4*)(pB + kk);
        areg[0] = qa[0]; areg[1] = qa[1]; areg[2] = qb[0]; areg[3] = qb[1];
    }
    asm volatile("s_waitcnt vmcnt(4)" ::: "memory");   // B(s0) landed; A(s0) may stay in flight
    __builtin_amdgcn_s_barrier();

    int buf = 0;
    for (int s = s0; s < s1; ++s) {
        // stage B(s+1) into other buffer (YG has a pad kb so s+1==313 is safe)
        {
            const bf16x8* src = YG + (size_t)(s + 1) * 1088;
            char* dst = (char*)&Bsh[buf ^ 1][0];
#pragma unroll
            for (int i = 0; i < 4; ++i) {
                int rr = wid + i * 4;
                gl_lds16(src + rr * 64 + lane, dst + rr * 1024);
            }
            if (wid == 0) gl_lds16(src + 1024 + lane, dst + 16384);
        }
        __builtin_amdgcn_sched_barrier(0);   // keep gl_lds older than the A-prefetch
        // prefetch A(s+1) direct to registers
        int4 anext[4];
        {
            int kk = (s + 1) * 32 + kgrp; kk = min(kk, 9992);
            const int4* qa = (const int4*)(pA + kk);
            const int4* qb = (const int4*)(pB + kk);
            anext[0] = qa[0]; anext[1] = qa[1]; anext[2] = qb[0]; anext[3] = qb[1];
        }
        // compute step s: convert A(s) (compiler auto-waits its loads), 17 col-tiles x 2 row-tiles
        bf16x8 fa0 = cvt_adj(areg[0], areg[1]);
        bf16x8 fa1 = cvt_adj(areg[2], areg[3]);
#pragma unroll
        for (int ct = 0; ct < 17; ++ct) {
            bf16x8 fb = Bsh[buf][l4 * 272 + ct * 16 + l15];
            acc[0][ct] = __builtin_amdgcn_mfma_f32_16x16x32_bf16(fa0, fb, acc[0][ct], 0, 0, 0);
            acc[1][ct] = __builtin_amdgcn_mfma_f32_16x16x32_bf16(fa1, fb, acc[1][ct], 0, 0, 0);
        }
        asm volatile("s_waitcnt vmcnt(4)" ::: "memory");   // B(s+1) landed; A(s+1) (4 newest) stays in flight
        __builtin_amdgcn_s_barrier();
        buf ^= 1;
        areg[0] = anext[0]; areg[1] = anext[1]; areg[2] = anext[2]; areg[3] = anext[3];
    }

    // ---- epilogue: atomic f32 partial accumulation ----
    int r0 = mb * 128 + wid * 32;
#pragma unroll
    for (int t = 0; t < 2; ++t) {
#pragma unroll
        for (int ct = 0; ct < 17; ++ct) {
            int col = ct * 16 + l15;
#pragma unroll
            for (int rg = 0; rg < 4; ++rg) {
                int row = r0 + t * 16 + l4 * 4 + rg;
                if (row < NN) atomicAdd(numv + (size_t)row * 272 + col, acc[t][ct][rg]);
            }
        }
    }
}

// ---------------- K5: out = num / max(den, 1e-30) ----------------
__global__ __launch_bounds__(256) void k_finalize(const float* __restrict__ numv,
                                                  float* __restrict__ out) {
    int idx = blockIdx.x * 256 + threadIdx.x;   // 0..639999 (float4 units)
    int i = idx >> 6, q = idx & 63;
    const float4* nrow = (const float4*)(numv + i * 272);
    float4 v = nrow[q];
    float den = numv[i * 272 + 256];
    float r = 1.0f / fmaxf(den, 1e-30f);
    float4 o;
    o.x = v.x * r; o.y = v.y * r; o.z = v.z * r; o.w = v.w * r;
    ((float4*)(out + i * 256))[q] = o;
}

extern "C" void kernel_launch(void* const* d_in, const int* in_sizes, int n_in,
                              void* d_out, int out_size, void* d_ws, size_t ws_size,
                              hipStream_t stream) {
    const float* X    = (const float*)d_in[0];
    const int*   adj  = (const int*)d_in[1];
    const float* W    = (const float*)d_in[3];
    const float* bvec = (const float*)d_in[4];
    const float* avec = (const float*)d_in[5];
    float* out = (float*)d_out;

    char* ws = (char*)d_ws;
    bf16x8* XG   = (bf16x8*)(ws + XG_OFF);
    bf16x8* WG   = (bf16x8*)(ws + WG_OFF);
    float*  inp  = (float*)(ws + INP_OFF);
    float*  evec = (float*)(ws + E_OFF);
    float*  hsv  = (float*)(ws + HS_OFF);
    float*  gv   = (float*)(ws + G_OFF);
    bf16x8* YG   = (bf16x8*)(ws + YG_OFF);
    float*  numv = (float*)(ws + NUM_OFF);

    hipMemsetAsync(ws + E_OFF, 0, E_SIZE + HS_SIZE, stream);
    hipMemsetAsync(ws + NUM_OFF, 0, NUM_SIZE, stream);

    k_build_xg<<<1250, 256, 0, stream>>>(X, XG);
    k_build_wg<<<32, 256, 0, stream>>>(W, WG);
    k_gemm1<<<125, 256, 0, stream>>>(XG, WG, bvec, avec, inp, evec, hsv);
    k_softmax_g<<<1, 1024, 0, stream>>>(evec, hsv, gv);
    k_build_yg<<<313, 256, 0, stream>>>(inp, gv, YG);
    k_attn_gemm<<<MB2 * KSPLIT, 256, 0, stream>>>(adj, YG, numv);
    k_finalize<<<2500, 256, 0, stream>>>(numv, out);
}

// Round 3
// 197.809 us; speedup vs baseline: 1.3867x; 1.1328x over previous
//
#include <hip/hip_runtime.h>
#include <hip/hip_bf16.h>
#include <cstdint>
#include <cstddef>

// Problem constants (shapes fixed by the reference)
#define NN      10000      // nodes (M == N == 10000)
#define DD      256        // feature dim
#define KSTEP64 157        // ceil(10016/64) K-steps of 64
#define MB2     79         // ceil(10000/128) m-blocks for big GEMM (BM=128)
#define KSPLIT  6          // 79*6 = 474 blocks (all co-resident at 2 blocks/CU)

typedef __bf16 bf16x8 __attribute__((ext_vector_type(8)));
typedef float  f32x4  __attribute__((ext_vector_type(4)));

// ---- workspace layout (bytes) ----
#define XG_OFF   0ull
#define XG_SIZE  (32ull * 10000 * 16)        // [q=kb*4+g][row] 16B chunks (bf16 X, MFMA-A layout)
#define WG_OFF   (XG_OFF + XG_SIZE)
#define WG_SIZE  (32ull * 256 * 16)          // [q][n] chunks (bf16 W, MFMA-B layout)
#define INP_OFF  (WG_OFF + WG_SIZE)
#define INP_SIZE (10000ull * 256 * 4)        // inp = X@W, f32
#define E_OFF    (INP_OFF + INP_SIZE)
#define E_SIZE   (10016ull * 4)
#define HS_OFF   (E_OFF + E_SIZE)
#define HS_SIZE  (10016ull * 4)
#define G_OFF    (HS_OFF + HS_SIZE)
#define G_SIZE   (10016ull * 4)
#define YG_OFF   (G_OFF + G_SIZE + 256ull)   // keep 256B alignment
#define YG_SIZE  (316ull * 1088 * 16)        // [kb][chunk]; kb 313..315 are zero pads (safe prefetch)
#define PN_OFF   (YG_OFF + YG_SIZE)
#define PN_SIZE  ((size_t)KSPLIT * 10000 * 272 * 4)  // per-kc partials: 256 numer cols + den at col 256

// async global(16B) -> LDS copy; dest = wave-uniform base + lane*16
__device__ __forceinline__ void gl_lds16(const void* g, void* lds) {
    __builtin_amdgcn_global_load_lds(
        (const __attribute__((address_space(1))) unsigned int*)g,
        (__attribute__((address_space(3))) unsigned int*)lds,
        16, 0, 0);
}

// ---------------- K0a: build XG (bf16 X in MFMA-A chunk layout) ----------------
__global__ __launch_bounds__(256) void k_build_xg(const float* __restrict__ X,
                                                  bf16x8* __restrict__ XG) {
    int idx = blockIdx.x * 256 + threadIdx.x;   // 0..319999
    int row = idx >> 5;
    int q   = idx & 31;
    const float* src = X + row * 256 + q * 8;
    bf16x8 v;
#pragma unroll
    for (int j = 0; j < 8; ++j) v[j] = (__bf16)src[j];
    XG[q * 10000 + row] = v;
}

// ---------------- K0b: build WG (bf16 W in MFMA-B chunk layout) ----------------
__global__ __launch_bounds__(256) void k_build_wg(const float* __restrict__ W,
                                                  bf16x8* __restrict__ WG) {
    int e = blockIdx.x * 256 + threadIdx.x;     // 0..8191
    int q = e >> 8;
    int n = e & 255;
    bf16x8 v;
#pragma unroll
    for (int j = 0; j < 8; ++j) v[j] = (__bf16)W[(q * 8 + j) * 256 + n];
    WG[e] = v;
}

// ---------------- K1: inp = X@W (MFMA), fused tanh/e/hsum (LDS cross-wave reduce) ----------------
__global__ __launch_bounds__(256) void k_gemm1(const bf16x8* __restrict__ XG,
                                               const bf16x8* __restrict__ WG,
                                               const float* __restrict__ bvec,
                                               const float* __restrict__ avec,
                                               float* __restrict__ inp,
                                               float* __restrict__ evec,
                                               float* __restrict__ hsumv) {
    __shared__ bf16x8 Ash[320];    // (g*80 + r)
    __shared__ bf16x8 Bsh[1024];   // (g*256 + n)
    __shared__ float ePart[4][80];
    __shared__ float hPart[4][80];
    int tid = threadIdx.x, wid = tid >> 6, lane = tid & 63;
    int l15 = lane & 15, l4 = lane >> 4;
    int mb = blockIdx.x;

    f32x4 acc[4][5];
#pragma unroll
    for (int c = 0; c < 4; ++c)
#pragma unroll
        for (int rt = 0; rt < 5; ++rt) acc[c][rt] = f32x4{0.f, 0.f, 0.f, 0.f};

    for (int kb = 0; kb < 8; ++kb) {
        for (int rr = wid; rr < 5; rr += 4) {
            int c = rr * 64 + lane;
            int g = c / 80, r = c - g * 80;
            gl_lds16(XG + ((kb * 4 + g) * 10000 + mb * 80 + r), (char*)Ash + rr * 1024);
        }
        for (int rr = wid; rr < 16; rr += 4)
            gl_lds16(WG + kb * 1024 + rr * 64 + lane, (char*)Bsh + rr * 1024);
        __syncthreads();

        bf16x8 af[5];
#pragma unroll
        for (int rt = 0; rt < 5; ++rt) af[rt] = Ash[l4 * 80 + rt * 16 + l15];
#pragma unroll
        for (int c = 0; c < 4; ++c) {
            bf16x8 bf = Bsh[l4 * 256 + (wid * 4 + c) * 16 + l15];
#pragma unroll
            for (int rt = 0; rt < 5; ++rt)
                acc[c][rt] = __builtin_amdgcn_mfma_f32_16x16x32_bf16(af[rt], bf, acc[c][rt], 0, 0, 0);
        }
        __syncthreads();
    }

    float pe[5][4], ph[5][4];
#pragma unroll
    for (int rt = 0; rt < 5; ++rt)
#pragma unroll
        for (int rg = 0; rg < 4; ++rg) { pe[rt][rg] = 0.f; ph[rt][rg] = 0.f; }

#pragma unroll
    for (int c = 0; c < 4; ++c) {
        int col = (wid * 4 + c) * 16 + l15;
        float av = avec[col];
        float bv = bvec[col];
#pragma unroll
        for (int rt = 0; rt < 5; ++rt) {
#pragma unroll
            for (int rg = 0; rg < 4; ++rg) {
                int row = mb * 80 + rt * 16 + l4 * 4 + rg;
                float v = acc[c][rt][rg];            // inp excludes bias (per reference)
                inp[row * 256 + col] = v;
                float h = tanhf(v + bv);
                pe[rt][rg] += h * av;
                ph[rt][rg] += h;
            }
        }
    }
#pragma unroll
    for (int rt = 0; rt < 5; ++rt) {
#pragma unroll
        for (int rg = 0; rg < 4; ++rg) {
            float se = pe[rt][rg], sh = ph[rt][rg];
#pragma unroll
            for (int m = 1; m < 16; m <<= 1) {
                se += __shfl_xor(se, m);
                sh += __shfl_xor(sh, m);
            }
            if (l15 == 0) {
                int lr = rt * 16 + l4 * 4 + rg;   // 0..79
                ePart[wid][lr] = se;
                hPart[wid][lr] = sh;
            }
        }
    }
    __syncthreads();
    if (tid < 80) {
        float e = ePart[0][tid] + ePart[1][tid] + ePart[2][tid] + ePart[3][tid];
        float h = hPart[0][tid] + hPart[1][tid] + hPart[2][tid] + hPart[3][tid];
        evec[mb * 80 + tid] = e;
        hsumv[mb * 80 + tid] = h;
    }
}

// ---------------- K2: global max of e over valid nodes, then g = exp(e-gmax) ----------------
__global__ __launch_bounds__(1024) void k_softmax_g(const float* __restrict__ evec,
                                                    const float* __restrict__ hsumv,
                                                    float* __restrict__ gv) {
    __shared__ float red[1024];
    int tid = threadIdx.x;
    float m = -3.0e38f;
    for (int i = tid; i < NN; i += 1024)
        if (hsumv[i] != 0.0f) m = fmaxf(m, evec[i]);
    red[tid] = m;
    __syncthreads();
    for (int s = 512; s > 0; s >>= 1) {
        if (tid < s) red[tid] = fmaxf(red[tid], red[tid + s]);
        __syncthreads();
    }
    float gmax = red[0];
    if (gmax < -1.0e37f) gmax = 0.0f;
    for (int i = tid; i < 10016; i += 1024) {
        float g = 0.0f;
        if (i < NN && hsumv[i] != 0.0f) g = expf(evec[i] - gmax);
        gv[i] = g;
    }
}

// ---------------- K3: build YG = pre-chunked bf16 B tiles for the big GEMM ----------------
// grid 316: kb >= 313 hits the k<NN guard everywhere -> zero pads for safe prefetch
__global__ __launch_bounds__(256) void k_build_yg(const float* __restrict__ inp,
                                                  const float* __restrict__ gv,
                                                  bf16x8* __restrict__ YG) {
    int kb = blockIdx.x;   // 0..315
    for (int c = threadIdx.x; c < 1088; c += 256) {
        int gq = c / 272, n = c - gq * 272;
        int k0 = kb * 32 + gq * 8;
        bf16x8 v;
#pragma unroll
        for (int j = 0; j < 8; ++j) {
            int k = k0 + j;
            float val = 0.0f;
            if (k < NN) {
                float gk = gv[k];
                if (n < 256) val = gk * inp[k * 256 + n];
                else if (n == 256) val = gk;
            }
            v[j] = (__bf16)val;
        }
        YG[kb * 1088 + c] = v;
    }
}

// ---- int32 {0,1} pair-of-int4 -> bf16x8 {0,1} fragment ----
__device__ __forceinline__ bf16x8 cvt_adj(int4 a, int4 b) {
    union { bf16x8 v; unsigned int u[4]; } r;
    r.u[0] = (a.x > 0 ? 0x3F80u : 0u) | (a.y > 0 ? 0x3F800000u : 0u);
    r.u[1] = (a.z > 0 ? 0x3F80u : 0u) | (a.w > 0 ? 0x3F800000u : 0u);
    r.u[2] = (b.x > 0 ? 0x3F80u : 0u) | (b.y > 0 ? 0x3F800000u : 0u);
    r.u[3] = (b.z > 0 ? 0x3F80u : 0u) | (b.w > 0 ? 0x3F800000u : 0u);
    return r.v;
}

// ---------------- K4: num_kc = adj @ Y  (BK=64, A->reg 1-step prefetch, B dbuf LDS) ----------------
// BM=128: 4 waves x 32 rows (2 row-tiles); all 17 col-tiles per wave; 68 MFMA/wave/step.
// Counted vmcnt(8): B(s+1) drained at the barrier, A(s+1) (8 newest loads) stays in flight.
__global__ __launch_bounds__(256, 2) void k_attn_gemm(const int* __restrict__ adj,
                                                      const bf16x8* __restrict__ YG,
                                                      float* __restrict__ pnum) {
    __shared__ bf16x8 Bsh[2][2176];   // double-buffered 64x272 bf16 tiles (69632 B)
    int tid = threadIdx.x, wid = tid >> 6, lane = tid & 63;
    int l15 = lane & 15, l4 = lane >> 4;
    int bid = blockIdx.x;
    int mb = bid / KSPLIT, kc = bid % KSPLIT;
    int s0 = (kc * KSTEP64) / KSPLIT, s1 = ((kc + 1) * KSTEP64) / KSPLIT;

    // A addressing: row = l15 (+16 for tile1), k-group = l4*8 (verified A-frag layout)
    int mrow = mb * 128 + wid * 32 + l15;
    const int* pA = adj + (size_t)min(mrow, NN - 1) * 10000;
    const int* pB = adj + (size_t)min(mrow + 16, NN - 1) * 10000;
    int kgrp = l4 * 8;

    f32x4 acc[2][17];
#pragma unroll
    for (int t = 0; t < 2; ++t)
#pragma unroll
        for (int ct = 0; ct < 17; ++ct) acc[t][ct] = f32x4{0.f, 0.f, 0.f, 0.f};

    int4 aA[8], aB[8];

    // ---- helpers (inlined) ----
    auto stageB = [&](int sTile, int bufIdx) {
        const bf16x8* src = YG + (size_t)sTile * 2176;
        char* dst = (char*)&Bsh[bufIdx][0];
#pragma unroll
        for (int i = 0; i < 9; ++i) {
            int rr = wid + i * 4;
            if (rr < 34) gl_lds16(src + rr * 64 + lane, dst + rr * 1024);
        }
    };
    auto loadA = [&](int sTile, int4* dstA) {
        int kk0 = min(sTile * 64 + kgrp, 9992);        // clamp safe: B is 0 for k>=NN
        int kk1 = min(sTile * 64 + 32 + kgrp, 9992);
        const int4* qa0 = (const int4*)(pA + kk0);
        const int4* qb0 = (const int4*)(pB + kk0);
        const int4* qa1 = (const int4*)(pA + kk1);
        const int4* qb1 = (const int4*)(pB + kk1);
        dstA[0] = qa0[0]; dstA[1] = qa0[1]; dstA[2] = qb0[0]; dstA[3] = qb0[1];
        dstA[4] = qa1[0]; dstA[5] = qa1[1]; dstA[6] = qb1[0]; dstA[7] = qb1[1];
    };
    auto compute = [&](const int4* aCur, int bufIdx) {
        bf16x8 f00 = cvt_adj(aCur[0], aCur[1]);   // kb-half 0, row-tile 0
        bf16x8 f01 = cvt_adj(aCur[2], aCur[3]);   // kb-half 0, row-tile 1
        bf16x8 f10 = cvt_adj(aCur[4], aCur[5]);   // kb-half 1, row-tile 0
        bf16x8 f11 = cvt_adj(aCur[6], aCur[7]);   // kb-half 1, row-tile 1
#pragma unroll
        for (int ct = 0; ct < 17; ++ct) {
            bf16x8 fb0 = Bsh[bufIdx][l4 * 272 + ct * 16 + l15];
            acc[0][ct] = __builtin_amdgcn_mfma_f32_16x16x32_bf16(f00, fb0, acc[0][ct], 0, 0, 0);
            acc[1][ct] = __builtin_amdgcn_mfma_f32_16x16x32_bf16(f01, fb0, acc[1][ct], 0, 0, 0);
            bf16x8 fb1 = Bsh[bufIdx][1088 + l4 * 272 + ct * 16 + l15];
            acc[0][ct] = __builtin_amdgcn_mfma_f32_16x16x32_bf16(f10, fb1, acc[0][ct], 0, 0, 0);
            acc[1][ct] = __builtin_amdgcn_mfma_f32_16x16x32_bf16(f11, fb1, acc[1][ct], 0, 0, 0);
        }
    };

    // ---- prologue: stage B(s0), issue A(s0) ----
    stageB(s0, 0);
    __builtin_amdgcn_sched_barrier(0);
    loadA(s0, aA);
    asm volatile("s_waitcnt vmcnt(8)" ::: "memory");   // B(s0) landed; A(s0) may stay in flight
    __builtin_amdgcn_s_barrier();

    // ---- main loop, 2-unrolled for A-reg ping-pong (no runtime-indexed reg arrays) ----
    int s = s0, buf = 0;
    while (s + 2 <= s1) {
        stageB(s + 1, buf ^ 1);
        __builtin_amdgcn_sched_barrier(0);
        loadA(s + 1, aB);
        __builtin_amdgcn_sched_barrier(0);
        compute(aA, buf);
        asm volatile("s_waitcnt vmcnt(8)" ::: "memory");
        __builtin_amdgcn_s_barrier();
        buf ^= 1; ++s;

        stageB(s + 1, buf ^ 1);
        __builtin_amdgcn_sched_barrier(0);
        loadA(s + 1, aA);
        __builtin_amdgcn_sched_barrier(0);
        compute(aB, buf);
        asm volatile("s_waitcnt vmcnt(8)" ::: "memory");
        __builtin_amdgcn_s_barrier();
        buf ^= 1; ++s;
    }
    if (s < s1) {   // odd tail: prefetches hit YG pad kbs (zeros) / clamped A — never consumed
        stageB(s1, buf ^ 1);
        __builtin_amdgcn_sched_barrier(0);
        loadA(s1, aB);
        __builtin_amdgcn_sched_barrier(0);
        compute(aA, buf);
    }

    // ---- epilogue: plain stores to per-kc partial buffer (no atomics, no pre-zero) ----
    float* base = pnum + (size_t)kc * 10000 * 272;
    int r0 = mb * 128 + wid * 32;
#pragma unroll
    for (int t = 0; t < 2; ++t) {
#pragma unroll
        for (int ct = 0; ct < 17; ++ct) {
            int col = ct * 16 + l15;
#pragma unroll
            for (int rg = 0; rg < 4; ++rg) {
                int row = r0 + t * 16 + l4 * 4 + rg;
                if (row < NN) base[(size_t)row * 272 + col] = acc[t][ct][rg];
            }
        }
    }
}

// ---------------- K5: out = (sum_kc num_kc) / max(sum_kc den_kc, 1e-30) ----------------
__global__ __launch_bounds__(256) void k_finalize(const float* __restrict__ pnum,
                                                  float* __restrict__ out) {
    int idx = blockIdx.x * 256 + threadIdx.x;   // 0..639999 (float4 units)
    int i = idx >> 6, q = idx & 63;
    float4 sv = {0.f, 0.f, 0.f, 0.f};
    float den = 0.f;
#pragma unroll
    for (int kc = 0; kc < KSPLIT; ++kc) {
        const float* row = pnum + ((size_t)kc * 10000 + i) * 272;
        float4 v = ((const float4*)row)[q];
        sv.x += v.x; sv.y += v.y; sv.z += v.z; sv.w += v.w;
        den += row[256];
    }
    float r = 1.0f / fmaxf(den, 1e-30f);
    float4 o;
    o.x = sv.x * r; o.y = sv.y * r; o.z = sv.z * r; o.w = sv.w * r;
    ((float4*)(out + (size_t)i * 256))[q] = o;
}

extern "C" void kernel_launch(void* const* d_in, const int* in_sizes, int n_in,
                              void* d_out, int out_size, void* d_ws, size_t ws_size,
                              hipStream_t stream) {
    const float* X    = (const float*)d_in[0];
    const int*   adj  = (const int*)d_in[1];
    const float* W    = (const float*)d_in[3];
    const float* bvec = (const float*)d_in[4];
    const float* avec = (const float*)d_in[5];
    float* out = (float*)d_out;

    char* ws = (char*)d_ws;
    bf16x8* XG   = (bf16x8*)(ws + XG_OFF);
    bf16x8* WG   = (bf16x8*)(ws + WG_OFF);
    float*  inp  = (float*)(ws + INP_OFF);
    float*  evec = (float*)(ws + E_OFF);
    float*  hsv  = (float*)(ws + HS_OFF);
    float*  gv   = (float*)(ws + G_OFF);
    bf16x8* YG   = (bf16x8*)(ws + YG_OFF);
    float*  pnum = (float*)(ws + PN_OFF);

    k_build_xg<<<1250, 256, 0, stream>>>(X, XG);
    k_build_wg<<<32, 256, 0, stream>>>(W, WG);
    k_gemm1<<<125, 256, 0, stream>>>(XG, WG, bvec, avec, inp, evec, hsv);
    k_softmax_g<<<1, 1024, 0, stream>>>(evec, hsv, gv);
    k_build_yg<<<316, 256, 0, stream>>>(inp, gv, YG);
    k_attn_gemm<<<MB2 * KSPLIT, 256, 0, stream>>>(adj, YG, pnum);
    k_finalize<<<2500, 256, 0, stream>>>(pnum, out);
}